// Round 7
// baseline (344.856 us; speedup 1.0000x reference)
//
#include <hip/hip_runtime.h>

typedef unsigned short u16;
typedef unsigned char u8;
typedef __attribute__((ext_vector_type(8))) short short8;
typedef __attribute__((ext_vector_type(4))) float f32x4;
typedef __attribute__((ext_vector_type(8))) int int8v;
typedef __attribute__((ext_vector_type(4))) int int4v;

#define LN_EPS 1e-5f
// fp8 exponent-shift scales (keep A ~3e-4 and v out of e4m3 subnormal floor)
#define SCALE_A 4096.f     // 2^12
#define SCALE_V 8.f        // 2^3
#define INV_SCALE_AV (1.f/32768.f)
#define MX_ONE 0x7F7F7F7Fu // e8m0 127 (=1.0)

__device__ __forceinline__ u16 f2bf(float f){
    union { float f; unsigned u; } c; c.f = f;
    unsigned u = c.u + 0x7FFFu + ((c.u >> 16) & 1u);
    return (u16)(u >> 16);
}
__device__ __forceinline__ float bf2f(u16 h){
    union { unsigned u; float f; } c; c.u = ((unsigned)h) << 16;
    return c.f;
}
__device__ __forceinline__ u8 f2fp8(float f){
    int r = __builtin_amdgcn_cvt_pk_fp8_f32(f, 0.f, 0, false);
    return (u8)(r & 0xFF);
}

enum { EPI_NONE=0, EPI_BIAS_RES, EPI_RELUSQ };
enum { OT_F32=0, OT_BF16=1, OT_FP8=2 };

__device__ __forceinline__ void gl2lds16(const void* g, void* lds){
    __builtin_amdgcn_global_load_lds(
        (const __attribute__((address_space(1))) unsigned*)g,
        (__attribute__((address_space(3))) unsigned*)lds, 16, 0, 0);
}

// ---------------- bf16 MFMA GEMM: C = A(MxK) @ B^T, BK=64 single-buffer ----------------
// LDS per matrix: [ks 0..7][row 0..127][8 u16] = 16 KB. 2 barriers/iter, 1 vm-drain.
template<int EPI, int OT>
__global__ __launch_bounds__(256)
void mgemm(const u16* __restrict__ A, const u16* __restrict__ B, void* __restrict__ Cv,
           int K, int lda, int ldb, int ldc,
           long sAb, long sBb, long sCb,
           const float* __restrict__ bias,
           const float* __restrict__ ext, int ldext,
           float scale)
{
    __shared__ u16 sA[8192];
    __shared__ u16 sB[8192];
    const int tid = threadIdx.x;
    const int m0 = blockIdx.y * 128, n0 = blockIdx.x * 128;
    const int z  = blockIdx.z;
    const u16* Az = A + (size_t)z * sAb;
    const u16* Bz = B + (size_t)z * sBb;

    const int lane = tid & 63, quad = lane >> 4, l15 = lane & 15;
    const int wave = tid >> 6;
    const int wm = (wave >> 1) * 64, wn = (wave & 1) * 64;

    const u16* gA[4]; const u16* gB[4]; int lo[4];
#pragma unroll
    for (int p = 0; p < 4; p++){
        const int c = tid + p * 256;           // chunk id 0..1023: row=c&127, ks=c>>7
        gA[p] = Az + (size_t)(m0 + (c & 127)) * lda + (c >> 7) * 8;
        gB[p] = Bz + (size_t)(n0 + (c & 127)) * ldb + (c >> 7) * 8;
        lo[p] = ((tid & 192) + p * 256) * 16;  // wave-uniform base; HW adds lane*16
    }

    f32x4 acc[4][4];
#pragma unroll
    for (int i = 0; i < 4; i++)
#pragma unroll
        for (int j = 0; j < 4; j++) acc[i][j] = (f32x4){0.f,0.f,0.f,0.f};

    for (int k0 = 0; k0 < K; k0 += 64){
#pragma unroll
        for (int p = 0; p < 4; p++){
            gl2lds16(gA[p] + k0, (char*)sA + lo[p]);
            gl2lds16(gB[p] + k0, (char*)sB + lo[p]);
        }
        __syncthreads();                       // vm-drain: staged data visible
#pragma unroll
        for (int kb = 0; kb < 2; kb++){        // two K=32 MFMA sub-steps
            const u16* fA = sA + (kb * 4 + quad) * 1024 + (wm + l15) * 8;
            const u16* fB = sB + (kb * 4 + quad) * 1024 + (wn + l15) * 8;
            short8 a[4], b[4];
#pragma unroll
            for (int t = 0; t < 4; t++){
                a[t] = *(const short8*)(fA + t * 128);
                b[t] = *(const short8*)(fB + t * 128);
            }
#pragma unroll
            for (int i = 0; i < 4; i++)
#pragma unroll
                for (int j = 0; j < 4; j++)
                    acc[i][j] = __builtin_amdgcn_mfma_f32_16x16x32_bf16(a[i], b[j], acc[i][j], 0, 0, 0);
        }
        __syncthreads();                       // all reads done; safe to restage
    }

    float* Cf = (float*)Cv; u16* Ch = (u16*)Cv; u8* C8 = (u8*)Cv;
    const size_t zc = (size_t)z * sCb;
#pragma unroll
    for (int i = 0; i < 4; i++){
#pragma unroll
        for (int j = 0; j < 4; j++){
            const int n = n0 + wn + j * 16 + l15;
            float bs = (EPI==EPI_BIAS_RES) ? bias[n] : 0.f;
#pragma unroll
            for (int r = 0; r < 4; r++){
                const int m = m0 + wm + i * 16 + quad * 4 + r;
                float v = acc[i][j][r] + bs;
                if (EPI==EPI_BIAS_RES)
                    v += ext[(size_t)m * ldext + n];
                if (EPI==EPI_RELUSQ){ float t = fmaxf(v * scale, 0.f); v = t * t * SCALE_A; }
                if (OT==OT_FP8)       C8[zc + (size_t)m * ldc + n] = f2fp8(v);
                else if (OT==OT_BF16) Ch[zc + (size_t)m * ldc + n] = f2bf(v);
                else                  Cf[zc + (size_t)m * ldc + n] = v;
            }
        }
    }
}

// ------- merged steps 3+4 (BK=64): h = relu(nrm@Wh^T+bh) -> v fp8|gate bf16 ; Z = relu(nrm@Wq^T+bq) -------
__global__ __launch_bounds__(256)
void mgemm_dual(const u16* __restrict__ Anrm, const u16* __restrict__ Wh,
                const u16* __restrict__ Wq,
                const float* __restrict__ bh, const float* __restrict__ bq,
                u8* __restrict__ v8, u16* __restrict__ gbf, u16* __restrict__ Zb)
{
    __shared__ u16 sA[8192];
    __shared__ u16 sB[8192];
    const int tid = threadIdx.x;
    const bool isZ = blockIdx.x >= 24;
    const u16* Bm = isZ ? Wq : Wh;
    const float* bias = isZ ? bq : bh;
    const int m0 = blockIdx.y * 128;
    const int n0 = (isZ ? (blockIdx.x - 24) : blockIdx.x) * 128;
    const int K = 512, lda = 512, ldb = 512;

    const int lane = tid & 63, quad = lane >> 4, l15 = lane & 15;
    const int wave = tid >> 6;
    const int wm = (wave >> 1) * 64, wn = (wave & 1) * 64;

    const u16* gA[4]; const u16* gB[4]; int lo[4];
#pragma unroll
    for (int p = 0; p < 4; p++){
        const int c = tid + p * 256;
        gA[p] = Anrm + (size_t)(m0 + (c & 127)) * lda + (c >> 7) * 8;
        gB[p] = Bm   + (size_t)(n0 + (c & 127)) * ldb + (c >> 7) * 8;
        lo[p] = ((tid & 192) + p * 256) * 16;
    }

    f32x4 acc[4][4];
#pragma unroll
    for (int i = 0; i < 4; i++)
#pragma unroll
        for (int j = 0; j < 4; j++) acc[i][j] = (f32x4){0.f,0.f,0.f,0.f};

    for (int k0 = 0; k0 < K; k0 += 64){
#pragma unroll
        for (int p = 0; p < 4; p++){
            gl2lds16(gA[p] + k0, (char*)sA + lo[p]);
            gl2lds16(gB[p] + k0, (char*)sB + lo[p]);
        }
        __syncthreads();
#pragma unroll
        for (int kb = 0; kb < 2; kb++){
            const u16* fA = sA + (kb * 4 + quad) * 1024 + (wm + l15) * 8;
            const u16* fB = sB + (kb * 4 + quad) * 1024 + (wn + l15) * 8;
            short8 a[4], b[4];
#pragma unroll
            for (int t = 0; t < 4; t++){
                a[t] = *(const short8*)(fA + t * 128);
                b[t] = *(const short8*)(fB + t * 128);
            }
#pragma unroll
            for (int i = 0; i < 4; i++)
#pragma unroll
                for (int j = 0; j < 4; j++)
                    acc[i][j] = __builtin_amdgcn_mfma_f32_16x16x32_bf16(a[i], b[j], acc[i][j], 0, 0, 0);
        }
        __syncthreads();
    }

#pragma unroll
    for (int i = 0; i < 4; i++){
#pragma unroll
        for (int j = 0; j < 4; j++){
            const int n = n0 + wn + j * 16 + l15;
            const float bs = bias[n];
#pragma unroll
            for (int r = 0; r < 4; r++){
                const int m = m0 + wm + i * 16 + quad * 4 + r;
                float v = fmaxf(acc[i][j][r] + bs, 0.f);
                if (isZ)            Zb[(size_t)m * 256 + n] = f2bf(v);
                else if (n < 1536)  v8[(size_t)m * 1536 + n] = f2fp8(v * SCALE_V);
                else                gbf[(size_t)m * 1536 + n - 1536] = f2bf(v);
            }
        }
    }
}

// ------- MX-scaled fp8 GEMM, K=128 per MFMA (Vg = (A@vT)*2^-15*gate) -------
__global__ __launch_bounds__(256)
void mgemm8mx(const u8* __restrict__ A, const u8* __restrict__ B, u16* __restrict__ C,
              int K, int lda, int ldb, int ldc,
              long sAb, long sBb, long sCb,
              const u16* __restrict__ gate, int ldext, long sEb)
{
    __shared__ u8 sA[16384];   // [row 0..127][128B], 16B chunks XOR-swizzled by row&7
    __shared__ u8 sB[16384];
    const int tid = threadIdx.x;
    const int m0 = blockIdx.y * 128, n0 = blockIdx.x * 128;
    const int z  = blockIdx.z;
    const u8* Az = A + (size_t)z * sAb;
    const u8* Bz = B + (size_t)z * sBb;

    const int lane = tid & 63, quad = lane >> 4, l15 = lane & 15;
    const int wave = tid >> 6;
    const int wm = (wave >> 1) * 64, wn = (wave & 1) * 64;

    const u8* gA[4]; const u8* gB[4]; int lo[4];
#pragma unroll
    for (int p = 0; p < 4; p++){
        const int r = p * 32 + (tid >> 3);
        const int j = (tid & 7) ^ (r & 7);
        gA[p] = Az + (size_t)(m0 + r) * lda + j * 16;
        gB[p] = Bz + (size_t)(n0 + r) * ldb + j * 16;
        lo[p] = p * 4096 + wave * 1024;
    }

    f32x4 acc[4][4];
#pragma unroll
    for (int i = 0; i < 4; i++)
#pragma unroll
        for (int j = 0; j < 4; j++) acc[i][j] = (f32x4){0.f,0.f,0.f,0.f};

    for (int k0 = 0; k0 < K; k0 += 128){
#pragma unroll
        for (int p = 0; p < 4; p++){
            gl2lds16(gA[p] + k0, (char*)sA + lo[p]);
            gl2lds16(gB[p] + k0, (char*)sB + lo[p]);
        }
        __syncthreads();
        int8v a[4], b[4];
#pragma unroll
        for (int i = 0; i < 4; i++){
            const int m = wm + i * 16 + l15;
            const int4v a0 = *(const int4v*)(sA + m * 128 + ((2*quad    ) ^ (m & 7)) * 16);
            const int4v a1 = *(const int4v*)(sA + m * 128 + ((2*quad + 1) ^ (m & 7)) * 16);
            a[i] = (int8v){a0[0],a0[1],a0[2],a0[3],a1[0],a1[1],a1[2],a1[3]};
            const int n = wn + i * 16 + l15;
            const int4v b0 = *(const int4v*)(sB + n * 128 + ((2*quad    ) ^ (n & 7)) * 16);
            const int4v b1 = *(const int4v*)(sB + n * 128 + ((2*quad + 1) ^ (n & 7)) * 16);
            b[i] = (int8v){b0[0],b0[1],b0[2],b0[3],b1[0],b1[1],b1[2],b1[3]};
        }
#pragma unroll
        for (int i = 0; i < 4; i++)
#pragma unroll
            for (int j = 0; j < 4; j++)
                acc[i][j] = __builtin_amdgcn_mfma_scale_f32_16x16x128_f8f6f4(
                    a[i], b[j], acc[i][j], 0, 0, 0, MX_ONE, 0, MX_ONE);
        __syncthreads();
    }

    const size_t zc = (size_t)z * sCb;
#pragma unroll
    for (int i = 0; i < 4; i++){
#pragma unroll
        for (int j = 0; j < 4; j++){
            const int n = n0 + wn + j * 16 + l15;
#pragma unroll
            for (int r = 0; r < 4; r++){
                const int m = m0 + wm + i * 16 + quad * 4 + r;
                float v = acc[i][j][r] * INV_SCALE_AV
                        * bf2f(gate[(size_t)z * sEb + (size_t)m * ldext + n]);
                C[zc + (size_t)m * ldc + n] = f2bf(v);
            }
        }
    }
}

// ---------------- Row LayerNorm over D=512, with partial-sum fusion ----------------
template<bool OUT_BF, bool POST_RES, int NSUM, bool PRE_RES>
__global__ __launch_bounds__(256)
void ln_k(const float* __restrict__ in, const float* __restrict__ g,
          const float* __restrict__ b, const float* __restrict__ res_post,
          const float* __restrict__ res_pre, const float* __restrict__ bias2,
          long pstride, void* __restrict__ out)
{
    const int row = blockIdx.x, tid = threadIdx.x;
    const size_t base = (size_t)row * 512 + tid * 2;
    float2 v = *(const float2*)(in + base);
#pragma unroll
    for (int p = 1; p < NSUM; p++){
        const float2 w = *(const float2*)(in + (size_t)p * pstride + base);
        v.x += w.x; v.y += w.y;
    }
    if (NSUM > 1){
        const float2 bb2 = *(const float2*)(bias2 + tid * 2);
        v.x += bb2.x; v.y += bb2.y;
    }
    if (PRE_RES){
        const float2 r = *(const float2*)(res_pre + base);
        v.x += r.x; v.y += r.y;
    }
    float s = v.x + v.y, ss = v.x * v.x + v.y * v.y;
#pragma unroll
    for (int off = 32; off > 0; off >>= 1){
        s  += __shfl_down(s,  off);
        ss += __shfl_down(ss, off);
    }
    __shared__ float sbuf[8], ssbuf[8];
    const int wid = tid >> 6, lane = tid & 63;
    if (lane == 0){ sbuf[wid] = s; ssbuf[wid] = ss; }
    __syncthreads();
    if (tid == 0){
        float S = 0.f, SS = 0.f;
#pragma unroll
        for (int i = 0; i < 4; i++){ S += sbuf[i]; SS += ssbuf[i]; }
        const float mean = S * (1.f/512.f);
        const float var  = SS * (1.f/512.f) - mean * mean;
        sbuf[4]  = mean;
        ssbuf[4] = rsqrtf(var + LN_EPS);
    }
    __syncthreads();
    const float mean = sbuf[4], rstd = ssbuf[4];
    const float2 gg = *(const float2*)(g + tid * 2);
    const float2 bb = *(const float2*)(b + tid * 2);
    float ox = (v.x - mean) * rstd * gg.x + bb.x;
    float oy = (v.y - mean) * rstd * gg.y + bb.y;
    if (POST_RES){
        const float2 r = *(const float2*)(res_post + base);
        ox += r.x; oy += r.y;
    }
    if (OUT_BF){
        unsigned pk = ((unsigned)f2bf(oy) << 16) | (unsigned)f2bf(ox);
        ((unsigned*)out)[(size_t)row * 256 + tid] = pk;
    } else {
        *(float2*)((float*)out + base) = make_float2(ox, oy);
    }
}

// ---------------- fused f32 -> bf16 casts + Wb transpose ----------------
__global__ __launch_bounds__(256)
void castall_k(const float* __restrict__ x, const float* __restrict__ Wm,
               const float* __restrict__ Wh, const float* __restrict__ Wq,
               const float* __restrict__ Wo, const float* __restrict__ Wb,
               u16* __restrict__ xb, u16* __restrict__ Wmb, u16* __restrict__ Whb,
               u16* __restrict__ Wqb, u16* __restrict__ Wob, u16* __restrict__ WbT)
{
    const int i = blockIdx.x * 256 + threadIdx.x;
    if (i >= 1736704){
        const int j = i - 1736704;
        if (j < 65536){
            const int e = j >> 8, d = j & 255;
            WbT[e * 256 + d] = f2bf(Wb[d * 256 + e]);
        }
        return;
    }
    const float* src; u16* dst; int off;
    if      (i < 1048576){ src = x;  dst = xb;  off = i; }
    else if (i < 1114112){ src = Wm; dst = Wmb; off = i - 1048576; }
    else if (i < 1507328){ src = Wh; dst = Whb; off = i - 1114112; }
    else if (i < 1540096){ src = Wq; dst = Wqb; off = i - 1507328; }
    else                 { src = Wo; dst = Wob; off = i - 1540096; }
    const float4 v = ((const float4*)src)[off];
    ushort4 o; o.x = f2bf(v.x); o.y = f2bf(v.y); o.z = f2bf(v.z); o.w = f2bf(v.w);
    ((ushort4*)dst)[off] = o;
}

// vT[b][h][s] = v[b][s][h], fp8, 64x64 tiles
__global__ __launch_bounds__(256)
void tr8_k(const u8* __restrict__ v, u8* __restrict__ vT, int S, int HID){
    const int b = blockIdx.z;
    const int h0 = blockIdx.x * 64, s0 = blockIdx.y * 64;
    __shared__ u8 t[64][68];
    const u8* vb = v + (size_t)b * S * HID;
    u8* vTb = vT + (size_t)b * HID * S;
    const int tid = threadIdx.x;
#pragma unroll
    for (int i = 0; i < 4; i++){
        int idx = tid + i * 256;
        int r = idx >> 4, c4 = (idx & 15) * 4;
        uchar4 u = *(const uchar4*)(vb + (size_t)(s0 + r) * HID + h0 + c4);
        t[r][c4] = u.x; t[r][c4+1] = u.y; t[r][c4+2] = u.z; t[r][c4+3] = u.w;
    }
    __syncthreads();
#pragma unroll
    for (int i = 0; i < 4; i++){
        int idx = tid + i * 256;
        int r = idx >> 4, c4 = (idx & 15) * 4;
        uchar4 u;
        u.x = t[c4][r]; u.y = t[c4+1][r]; u.z = t[c4+2][r]; u.w = t[c4+3][r];
        *(uchar4*)(vTb + (size_t)(h0 + r) * S + s0 + c4) = u;
    }
}

extern "C" void kernel_launch(void* const* d_in, const int* in_sizes, int n_in,
                              void* d_out, int out_size, void* d_ws, size_t ws_size,
                              hipStream_t stream)
{
    const float* x  = (const float*)d_in[0];
    const float* Wm = (const float*)d_in[1];
    const float* bm = (const float*)d_in[2];
    const float* g1 = (const float*)d_in[3];
    const float* b1 = (const float*)d_in[4];
    const float* Wh = (const float*)d_in[5];
    const float* bh = (const float*)d_in[6];
    const float* Wq = (const float*)d_in[7];
    const float* bq = (const float*)d_in[8];
    const float* Wb = (const float*)d_in[9];
    const float* Wo = (const float*)d_in[10];
    const float* bo = (const float*)d_in[11];
    const float* g2 = (const float*)d_in[12];
    const float* b2 = (const float*)d_in[13];
    float* out = (float*)d_out;
    (void)in_sizes; (void)n_in; (void)out_size; (void)ws_size;

    const int Bn=4, S=2048, D=512, QKD=256, HID=1536, H2=3072;
    const int M = Bn * S; // 8192
    const long MD = (long)M * D;

    char* p = (char*)d_ws;
    auto alloc = [&](size_t bytes)->void*{ void* r = p; p += (bytes + 255) & ~(size_t)255; return r; };
    u16*  xbf  = (u16*) alloc((size_t)M*D*2);     // later reused as normed_bf
    u16*  Wmbf = (u16*) alloc((size_t)D*D*2);
    u16*  Whbf = (u16*) alloc((size_t)H2*D*2);
    u16*  Wqbf = (u16*) alloc((size_t)QKD*D*2);
    u16*  Wobf = (u16*) alloc((size_t)D*HID*2);
    u16*  WbT  = (u16*) alloc((size_t)QKD*QKD*2);
    float* ybuf= (float*)alloc((size_t)MD*4*2);   // 2 split-K partials (Wo)
    u16*  Zb   = (u16*) alloc((size_t)M*QKD*2);
    u16*  ZWbb = (u16*) alloc((size_t)M*QKD*2);
    u8*   v8   = (u8*)  alloc((size_t)M*HID);
    u16*  gbf  = (u16*) alloc((size_t)M*HID*2);
    u8*   vT8  = (u8*)  alloc((size_t)M*HID);
    u8*   A8   = (u8*)  alloc((size_t)M*S);
    u16*  Vgbf = (u16*) alloc((size_t)M*HID*2);
    u16*  nrm  = xbf;

    dim3 blk(256);

    // 0. casts + Wb transpose
    castall_k<<<dim3(7040), blk, 0, stream>>>(x, Wm, Wh, Wq, Wo, Wb,
                                              xbf, Wmbf, Whbf, Wqbf, Wobf, WbT);
    // 1. y = x@Wm^T + bm + x   (fused epilogue, fp32)
    mgemm<EPI_BIAS_RES,OT_F32><<<dim3(D/128, M/128, 1), blk, 0, stream>>>(
        xbf, Wmbf, ybuf, D, D, D, D, 0,0,0, bm, x, D, 1.f);
    // 2. normed = LN(y) -> bf16
    ln_k<true,false,1,false><<<dim3(M), blk, 0, stream>>>(
        ybuf, g1, b1, nullptr, nullptr, nullptr, 0, nrm);
    // 3+4 merged: h -> v fp8|gate bf16 ; Z -> bf16
    mgemm_dual<<<dim3(26, M/128), blk, 0, stream>>>(
        nrm, Whbf, Wqbf, bh, bq, v8, gbf, Zb);
    // 5. ZWb = Z @ Wb -> bf16
    mgemm<EPI_NONE,OT_BF16><<<dim3(QKD/128, M/128, 1), blk, 0, stream>>>(
        Zb, WbT, ZWbb, QKD, QKD, QKD, QKD, 0,0,0, nullptr, nullptr, 0, 1.f);
    // 6a. A = relu(ZWb_b @ Z_b^T / S)^2 * 2^12 -> fp8, batched over z
    mgemm<EPI_RELUSQ,OT_FP8><<<dim3(S/128, S/128, Bn), blk, 0, stream>>>(
        ZWbb, Zb, A8, QKD, QKD, QKD, S,
        (long)S*QKD, (long)S*QKD, (long)S*S,
        nullptr, nullptr, 0, 1.f/(float)S);
    // 6b. vT = transpose(v) per batch (fp8)
    tr8_k<<<dim3(HID/64, S/64, Bn), blk, 0, stream>>>(v8, vT8, S, HID);
    // 6c. Vg = (A @ v) * 2^-15 * gate -> bf16, MX-scaled fp8 K=128
    mgemm8mx<<<dim3(HID/128, S/128, Bn), blk, 0, stream>>>(
        A8, vT8, Vgbf, S, S, S, HID,
        (long)S*S, (long)HID*S, (long)S*HID,
        gbf, HID, (long)S*HID);
    // 7. t partials = Vg@Wo^T  (split-K z=2, fp32; bias in LN2)
    mgemm<EPI_NONE,OT_F32><<<dim3(D/128, M/128, 2), blk, 0, stream>>>(
        Vgbf, Wobf, ybuf, HID/2, HID, HID, D, 768, 768, MD,
        nullptr, nullptr, 0, 1.f);
    // 8. out = LN(p0+p1 + bo) + x
    ln_k<false,true,2,false><<<dim3(M), blk, 0, stream>>>(
        ybuf, g2, b2, x, nullptr, bo, MD, out);
}

// Round 9
// 312.738 us; speedup vs baseline: 1.1027x; 1.1027x over previous
//
#include <hip/hip_runtime.h>

typedef unsigned short u16;
typedef unsigned char u8;
typedef __attribute__((ext_vector_type(8))) short short8;
typedef __attribute__((ext_vector_type(4))) float f32x4;
typedef __attribute__((ext_vector_type(8))) int int8v;
typedef __attribute__((ext_vector_type(4))) int int4v;

#define LN_EPS 1e-5f
// fp8 exponent-shift scales (keep values out of e4m3 subnormal floor 2^-6)
#define SCALE_A 4096.f       // A = relu(QK)^2 * 2^12
#define SCALE_V 8.f          // v * 2^3
#define INV_SCALE_AV (1.f/32768.f)
#define SCALE_NRM 4.f        // nrm * 2^2
#define SCALE_WH 512.f       // Wh * 2^9
#define INV_SCALE_H (1.f/2048.f)  // undo 2^11 for h = nrm8 @ Wh8^T
#define MX_ONE 0x7F7F7F7Fu   // e8m0 127 (=1.0)

__device__ __forceinline__ u16 f2bf(float f){
    union { float f; unsigned u; } c; c.f = f;
    unsigned u = c.u + 0x7FFFu + ((c.u >> 16) & 1u);
    return (u16)(u >> 16);
}
__device__ __forceinline__ float bf2f(u16 h){
    union { unsigned u; float f; } c; c.u = ((unsigned)h) << 16;
    return c.f;
}
__device__ __forceinline__ u8 f2fp8(float f){
    int r = __builtin_amdgcn_cvt_pk_fp8_f32(f, 0.f, 0, false);
    return (u8)(r & 0xFF);
}
__device__ __forceinline__ u16 f2fp8x2(float a, float b){
    int r = __builtin_amdgcn_cvt_pk_fp8_f32(a, b, 0, false);
    return (u16)(r & 0xFFFF);
}

enum { EPI_NONE=0, EPI_BIAS_RES, EPI_BIAS_RELU, EPI_RELUSQ };
enum { OT_F32=0, OT_BF16=1, OT_FP8=2 };

__device__ __forceinline__ void gl2lds16(const void* g, void* lds){
    __builtin_amdgcn_global_load_lds(
        (const __attribute__((address_space(1))) unsigned*)g,
        (__attribute__((address_space(3))) unsigned*)lds, 16, 0, 0);
}

// ---------------- bf16 MFMA GEMM: C = A(MxK) @ B^T ----------------
// R4-style: BK=32, single-buffer, 16 KB LDS (measured best across R2..R7).
template<int EPI, int OT>
__global__ __launch_bounds__(256)
void mgemm(const u16* __restrict__ A, const u16* __restrict__ B, void* __restrict__ Cv,
           int K, int lda, int ldb, int ldc,
           long sAb, long sBb, long sCb,
           const float* __restrict__ bias,
           const float* __restrict__ ext, int ldext,
           float scale)
{
    __shared__ u16 sA[4096];   // [ks 0..3][m 0..127][8]
    __shared__ u16 sB[4096];
    const int tid = threadIdx.x;
    const int m0 = blockIdx.y * 128, n0 = blockIdx.x * 128;
    const int z  = blockIdx.z;
    const u16* Az = A + (size_t)z * sAb;
    const u16* Bz = B + (size_t)z * sBb;

    const int lane = tid & 63, quad = lane >> 4, l15 = lane & 15;
    const int wave = tid >> 6;
    const int wm = (wave >> 1) * 64, wn = (wave & 1) * 64;

    const u16* gA[2]; const u16* gB[2]; int lo[2];
#pragma unroll
    for (int r = 0; r < 2; r++){
        const int c = tid + r * 256;            // chunk id 0..511
        gA[r] = Az + (size_t)(m0 + (c & 127)) * lda + (c >> 7) * 8;
        gB[r] = Bz + (size_t)(n0 + (c & 127)) * ldb + (c >> 7) * 8;
        lo[r] = ((tid & 192) + r * 256) * 16;   // wave-uniform LDS byte base
    }

    f32x4 acc[4][4];
#pragma unroll
    for (int i = 0; i < 4; i++)
#pragma unroll
        for (int j = 0; j < 4; j++) acc[i][j] = (f32x4){0.f,0.f,0.f,0.f};

    const u16* fA = sA + quad * 1024 + (wm + l15) * 8;
    const u16* fB = sB + quad * 1024 + (wn + l15) * 8;

    for (int k0 = 0; k0 < K; k0 += 32){
#pragma unroll
        for (int r = 0; r < 2; r++){
            gl2lds16(gA[r] + k0, (char*)sA + lo[r]);
            gl2lds16(gB[r] + k0, (char*)sB + lo[r]);
        }
        __syncthreads();
        short8 a[4], b[4];
#pragma unroll
        for (int t = 0; t < 4; t++){
            a[t] = *(const short8*)(fA + t * 128);
            b[t] = *(const short8*)(fB + t * 128);
        }
#pragma unroll
        for (int i = 0; i < 4; i++)
#pragma unroll
            for (int j = 0; j < 4; j++)
                acc[i][j] = __builtin_amdgcn_mfma_f32_16x16x32_bf16(a[i], b[j], acc[i][j], 0, 0, 0);
        __syncthreads();
    }

    float* Cf = (float*)Cv; u16* Ch = (u16*)Cv; u8* C8 = (u8*)Cv;
    const size_t zc = (size_t)z * sCb;
#pragma unroll
    for (int i = 0; i < 4; i++){
#pragma unroll
        for (int j = 0; j < 4; j++){
            const int n = n0 + wn + j * 16 + l15;
            float bs = (EPI==EPI_BIAS_RES || EPI==EPI_BIAS_RELU) ? bias[n] : 0.f;
#pragma unroll
            for (int r = 0; r < 4; r++){
                const int m = m0 + wm + i * 16 + quad * 4 + r;
                float v = acc[i][j][r] + bs;
                if (EPI==EPI_BIAS_RES)
                    v += ext[(size_t)m * ldext + n];
                if (EPI==EPI_BIAS_RELU)
                    v = fmaxf(v, 0.f);
                if (EPI==EPI_RELUSQ){ float t = fmaxf(v * scale, 0.f); v = t * t * SCALE_A; }
                if (OT==OT_FP8)       C8[zc + (size_t)m * ldc + n] = f2fp8(v);
                else if (OT==OT_BF16) Ch[zc + (size_t)m * ldc + n] = f2bf(v);
                else                  Cf[zc + (size_t)m * ldc + n] = v;
            }
        }
    }
}

// ------- dual bf16 GEMM: gate = relu(nrm@Whg^T + bhg) [x=0..11] ; Z = relu(nrm@Wq^T + bq) [x=12..13] -------
__global__ __launch_bounds__(256)
void mgemm_dual(const u16* __restrict__ Anrm, const u16* __restrict__ Whg,
                const u16* __restrict__ Wq,
                const float* __restrict__ bhg, const float* __restrict__ bq,
                u16* __restrict__ gbf, u16* __restrict__ Zb)
{
    __shared__ u16 sA[4096];
    __shared__ u16 sB[4096];
    const int tid = threadIdx.x;
    const bool isZ = blockIdx.x >= 12;
    const u16* Bm = isZ ? Wq : Whg;
    const float* bias = isZ ? bq : bhg;
    const int m0 = blockIdx.y * 128;
    const int n0 = (isZ ? (blockIdx.x - 12) : blockIdx.x) * 128;
    const int K = 512, lda = 512, ldb = 512;

    const int lane = tid & 63, quad = lane >> 4, l15 = lane & 15;
    const int wave = tid >> 6;
    const int wm = (wave >> 1) * 64, wn = (wave & 1) * 64;

    const u16* gA[2]; const u16* gB[2]; int lo[2];
#pragma unroll
    for (int r = 0; r < 2; r++){
        const int c = tid + r * 256;
        gA[r] = Anrm + (size_t)(m0 + (c & 127)) * lda + (c >> 7) * 8;
        gB[r] = Bm   + (size_t)(n0 + (c & 127)) * ldb + (c >> 7) * 8;
        lo[r] = ((tid & 192) + r * 256) * 16;
    }

    f32x4 acc[4][4];
#pragma unroll
    for (int i = 0; i < 4; i++)
#pragma unroll
        for (int j = 0; j < 4; j++) acc[i][j] = (f32x4){0.f,0.f,0.f,0.f};

    const u16* fA = sA + quad * 1024 + (wm + l15) * 8;
    const u16* fB = sB + quad * 1024 + (wn + l15) * 8;

    for (int k0 = 0; k0 < K; k0 += 32){
#pragma unroll
        for (int r = 0; r < 2; r++){
            gl2lds16(gA[r] + k0, (char*)sA + lo[r]);
            gl2lds16(gB[r] + k0, (char*)sB + lo[r]);
        }
        __syncthreads();
        short8 a[4], b[4];
#pragma unroll
        for (int t = 0; t < 4; t++){
            a[t] = *(const short8*)(fA + t * 128);
            b[t] = *(const short8*)(fB + t * 128);
        }
#pragma unroll
        for (int i = 0; i < 4; i++)
#pragma unroll
            for (int j = 0; j < 4; j++)
                acc[i][j] = __builtin_amdgcn_mfma_f32_16x16x32_bf16(a[i], b[j], acc[i][j], 0, 0, 0);
        __syncthreads();
    }

#pragma unroll
    for (int i = 0; i < 4; i++){
#pragma unroll
        for (int j = 0; j < 4; j++){
            const int n = n0 + wn + j * 16 + l15;
            const float bs = bias[n];
#pragma unroll
            for (int r = 0; r < 4; r++){
                const int m = m0 + wm + i * 16 + quad * 4 + r;
                float v = fmaxf(acc[i][j][r] + bs, 0.f);
                if (isZ) Zb[(size_t)m * 256 + n] = f2bf(v);
                else     gbf[(size_t)m * 1536 + n] = f2bf(v);
            }
        }
    }
}

// ------- MX-scaled fp8 GEMM, K=128 per MFMA -------
// VOUT=true (3a): v = relu(acc*2^-11 + bh[n]) -> fp8*8 (N=1536 v-half only).
// VOUT=false (6c): Vg = acc*2^-15 * gate -> bf16.
template<bool VOUT>
__global__ __launch_bounds__(256)
void mgemm8mx(const u8* __restrict__ A, const u8* __restrict__ B, u16* __restrict__ C,
              int K, int lda, int ldb, int ldc,
              long sAb, long sBb, long sCb,
              const u16* __restrict__ gate, int ldext, long sEb,
              const float* __restrict__ bias, u8* __restrict__ vout)
{
    __shared__ u8 sA[16384];   // [row 0..127][128B], 16B chunks XOR-swizzled by row&7
    __shared__ u8 sB[16384];
    const int tid = threadIdx.x;
    const int m0 = blockIdx.y * 128, n0 = blockIdx.x * 128;
    const int z  = blockIdx.z;
    const u8* Az = A + (size_t)z * sAb;
    const u8* Bz = B + (size_t)z * sBb;

    const int lane = tid & 63, quad = lane >> 4, l15 = lane & 15;
    const int wave = tid >> 6;
    const int wm = (wave >> 1) * 64, wn = (wave & 1) * 64;

    const u8* gA[4]; const u8* gB[4]; int lo[4];
#pragma unroll
    for (int p = 0; p < 4; p++){
        const int r = p * 32 + (tid >> 3);
        const int j = (tid & 7) ^ (r & 7);
        gA[p] = Az + (size_t)(m0 + r) * lda + j * 16;
        gB[p] = Bz + (size_t)(n0 + r) * ldb + j * 16;
        lo[p] = p * 4096 + wave * 1024;
    }

    f32x4 acc[4][4];
#pragma unroll
    for (int i = 0; i < 4; i++)
#pragma unroll
        for (int j = 0; j < 4; j++) acc[i][j] = (f32x4){0.f,0.f,0.f,0.f};

    for (int k0 = 0; k0 < K; k0 += 128){
#pragma unroll
        for (int p = 0; p < 4; p++){
            gl2lds16(gA[p] + k0, (char*)sA + lo[p]);
            gl2lds16(gB[p] + k0, (char*)sB + lo[p]);
        }
        __syncthreads();
        int8v a[4], b[4];
#pragma unroll
        for (int i = 0; i < 4; i++){
            const int m = wm + i * 16 + l15;
            const int4v a0 = *(const int4v*)(sA + m * 128 + ((2*quad    ) ^ (m & 7)) * 16);
            const int4v a1 = *(const int4v*)(sA + m * 128 + ((2*quad + 1) ^ (m & 7)) * 16);
            a[i] = (int8v){a0[0],a0[1],a0[2],a0[3],a1[0],a1[1],a1[2],a1[3]};
            const int n = wn + i * 16 + l15;
            const int4v b0 = *(const int4v*)(sB + n * 128 + ((2*quad    ) ^ (n & 7)) * 16);
            const int4v b1 = *(const int4v*)(sB + n * 128 + ((2*quad + 1) ^ (n & 7)) * 16);
            b[i] = (int8v){b0[0],b0[1],b0[2],b0[3],b1[0],b1[1],b1[2],b1[3]};
        }
#pragma unroll
        for (int i = 0; i < 4; i++)
#pragma unroll
            for (int j = 0; j < 4; j++)
                acc[i][j] = __builtin_amdgcn_mfma_scale_f32_16x16x128_f8f6f4(
                    a[i], b[j], acc[i][j], 0, 0, 0, MX_ONE, 0, MX_ONE);
        __syncthreads();
    }

    const size_t zc = (size_t)z * sCb;
#pragma unroll
    for (int i = 0; i < 4; i++){
#pragma unroll
        for (int j = 0; j < 4; j++){
            const int n = n0 + wn + j * 16 + l15;
#pragma unroll
            for (int r = 0; r < 4; r++){
                const int m = m0 + wm + i * 16 + quad * 4 + r;
                if (VOUT){
                    float h = fmaxf(acc[i][j][r] * INV_SCALE_H + bias[n], 0.f);
                    vout[(size_t)m * 1536 + n] = f2fp8(h * SCALE_V);
                } else {
                    float v = acc[i][j][r] * INV_SCALE_AV
                            * bf2f(gate[(size_t)z * sEb + (size_t)m * ldext + n]);
                    C[zc + (size_t)m * ldc + n] = f2bf(v);
                }
            }
        }
    }
}

// ---------------- LN1: nrm = LN(y; g1,b1) -> bf16 AND fp8(*4) ----------------
__global__ __launch_bounds__(256)
void ln1_k(const float* __restrict__ in, const float* __restrict__ g,
           const float* __restrict__ b, u16* __restrict__ nbf, u16* __restrict__ n8)
{
    const int row = blockIdx.x, tid = threadIdx.x;
    const size_t base = (size_t)row * 512 + tid * 2;
    const float2 v = *(const float2*)(in + base);
    float s = v.x + v.y, ss = v.x * v.x + v.y * v.y;
#pragma unroll
    for (int off = 32; off > 0; off >>= 1){
        s  += __shfl_down(s,  off);
        ss += __shfl_down(ss, off);
    }
    __shared__ float sbuf[8], ssbuf[8];
    const int wid = tid >> 6, lane = tid & 63;
    if (lane == 0){ sbuf[wid] = s; ssbuf[wid] = ss; }
    __syncthreads();
    if (tid == 0){
        float S = 0.f, SS = 0.f;
#pragma unroll
        for (int i = 0; i < 4; i++){ S += sbuf[i]; SS += ssbuf[i]; }
        const float mean = S * (1.f/512.f);
        const float var  = SS * (1.f/512.f) - mean * mean;
        sbuf[4]  = mean;
        ssbuf[4] = rsqrtf(var + LN_EPS);
    }
    __syncthreads();
    const float mean = sbuf[4], rstd = ssbuf[4];
    const float2 gg = *(const float2*)(g + tid * 2);
    const float2 bb = *(const float2*)(b + tid * 2);
    const float ox = (v.x - mean) * rstd * gg.x + bb.x;
    const float oy = (v.y - mean) * rstd * gg.y + bb.y;
    ((unsigned*)nbf)[(size_t)row * 256 + tid] =
        ((unsigned)f2bf(oy) << 16) | (unsigned)f2bf(ox);
    n8[(size_t)row * 256 + tid] = f2fp8x2(ox * SCALE_NRM, oy * SCALE_NRM);
}

// ---------------- LN2: out = LN(bf(p0)+bf(p1)+bo; g2,b2) + x ----------------
__global__ __launch_bounds__(256)
void ln2_k(const u16* __restrict__ pa, long pstride,
           const float* __restrict__ bias2,
           const float* __restrict__ g, const float* __restrict__ b,
           const float* __restrict__ x, float* __restrict__ out)
{
    const int row = blockIdx.x, tid = threadIdx.x;
    const size_t base = (size_t)row * 512 + tid * 2;
    const unsigned p0 = ((const unsigned*)pa)[(size_t)row * 256 + tid];
    const unsigned p1 = ((const unsigned*)(pa + pstride))[(size_t)row * 256 + tid];
    const float2 bb2 = *(const float2*)(bias2 + tid * 2);
    float2 v;
    v.x = bf2f((u16)p0) + bf2f((u16)p1) + bb2.x;
    v.y = bf2f((u16)(p0 >> 16)) + bf2f((u16)(p1 >> 16)) + bb2.y;
    float s = v.x + v.y, ss = v.x * v.x + v.y * v.y;
#pragma unroll
    for (int off = 32; off > 0; off >>= 1){
        s  += __shfl_down(s,  off);
        ss += __shfl_down(ss, off);
    }
    __shared__ float sbuf[8], ssbuf[8];
    const int wid = tid >> 6, lane = tid & 63;
    if (lane == 0){ sbuf[wid] = s; ssbuf[wid] = ss; }
    __syncthreads();
    if (tid == 0){
        float S = 0.f, SS = 0.f;
#pragma unroll
        for (int i = 0; i < 4; i++){ S += sbuf[i]; SS += ssbuf[i]; }
        const float mean = S * (1.f/512.f);
        const float var  = SS * (1.f/512.f) - mean * mean;
        sbuf[4]  = mean;
        ssbuf[4] = rsqrtf(var + LN_EPS);
    }
    __syncthreads();
    const float mean = sbuf[4], rstd = ssbuf[4];
    const float2 gg = *(const float2*)(g + tid * 2);
    const float2 bb = *(const float2*)(b + tid * 2);
    const float2 r = *(const float2*)(x + base);
    float2 o;
    o.x = (v.x - mean) * rstd * gg.x + bb.x + r.x;
    o.y = (v.y - mean) * rstd * gg.y + bb.y + r.y;
    *(float2*)(out + base) = o;
}

// -------- fused casts: x,Wm,Wq,Wo -> bf16 ; Wh v-half -> fp8(*512), gate-half -> bf16 ; WbT --------
__global__ __launch_bounds__(256)
void castall_k(const float* __restrict__ x, const float* __restrict__ Wm,
               const float* __restrict__ Wh, const float* __restrict__ Wq,
               const float* __restrict__ Wo, const float* __restrict__ Wb,
               u16* __restrict__ xb, u16* __restrict__ Wmb, u8* __restrict__ Wh8,
               u16* __restrict__ Whgb,
               u16* __restrict__ Wqb, u16* __restrict__ Wob, u16* __restrict__ WbT)
{
    const int i = blockIdx.x * 256 + threadIdx.x;
    if (i >= 1736704){
        const int j = i - 1736704;
        if (j < 65536){
            const int e = j >> 8, d = j & 255;
            WbT[e * 256 + d] = f2bf(Wb[d * 256 + e]);
        }
        return;
    }
    if (i >= 1114112 && i < 1310720){       // Wh rows 0..1535 (v-half) -> fp8 * 512
        const int off = i - 1114112;
        const float4 v = ((const float4*)Wh)[off];
        unsigned r0 = (unsigned)f2fp8x2(v.x * SCALE_WH, v.y * SCALE_WH);
        unsigned r1 = (unsigned)f2fp8x2(v.z * SCALE_WH, v.w * SCALE_WH);
        ((unsigned*)Wh8)[off] = r0 | (r1 << 16);
        return;
    }
    const float* src; u16* dst; int off;
    if      (i < 1048576){ src = x;  dst = xb;   off = i; }
    else if (i < 1114112){ src = Wm; dst = Wmb;  off = i - 1048576; }
    else if (i < 1507328){ src = Wh + 786432; dst = Whgb; off = i - 1310720; }  // gate-half -> bf16
    else if (i < 1540096){ src = Wq; dst = Wqb;  off = i - 1507328; }
    else                 { src = Wo; dst = Wob;  off = i - 1540096; }
    const float4 v = ((const float4*)src)[off];
    ushort4 o; o.x = f2bf(v.x); o.y = f2bf(v.y); o.z = f2bf(v.z); o.w = f2bf(v.w);
    ((ushort4*)dst)[off] = o;
}

// vT[b][h][s] = v[b][s][h], fp8, 64x64 tiles
__global__ __launch_bounds__(256)
void tr8_k(const u8* __restrict__ v, u8* __restrict__ vT, int S, int HID){
    const int b = blockIdx.z;
    const int h0 = blockIdx.x * 64, s0 = blockIdx.y * 64;
    __shared__ u8 t[64][68];
    const u8* vb = v + (size_t)b * S * HID;
    u8* vTb = vT + (size_t)b * HID * S;
    const int tid = threadIdx.x;
#pragma unroll
    for (int i = 0; i < 4; i++){
        int idx = tid + i * 256;
        int r = idx >> 4, c4 = (idx & 15) * 4;
        uchar4 u = *(const uchar4*)(vb + (size_t)(s0 + r) * HID + h0 + c4);
        t[r][c4] = u.x; t[r][c4+1] = u.y; t[r][c4+2] = u.z; t[r][c4+3] = u.w;
    }
    __syncthreads();
#pragma unroll
    for (int i = 0; i < 4; i++){
        int idx = tid + i * 256;
        int r = idx >> 4, c4 = (idx & 15) * 4;
        uchar4 u;
        u.x = t[c4][r]; u.y = t[c4+1][r]; u.z = t[c4+2][r]; u.w = t[c4+3][r];
        *(uchar4*)(vTb + (size_t)(h0 + r) * S + s0 + c4) = u;
    }
}

extern "C" void kernel_launch(void* const* d_in, const int* in_sizes, int n_in,
                              void* d_out, int out_size, void* d_ws, size_t ws_size,
                              hipStream_t stream)
{
    const float* x  = (const float*)d_in[0];
    const float* Wm = (const float*)d_in[1];
    const float* bm = (const float*)d_in[2];
    const float* g1 = (const float*)d_in[3];
    const float* b1 = (const float*)d_in[4];
    const float* Wh = (const float*)d_in[5];
    const float* bh = (const float*)d_in[6];
    const float* Wq = (const float*)d_in[7];
    const float* bq = (const float*)d_in[8];
    const float* Wb = (const float*)d_in[9];
    const float* Wo = (const float*)d_in[10];
    const float* bo = (const float*)d_in[11];
    const float* g2 = (const float*)d_in[12];
    const float* b2 = (const float*)d_in[13];
    float* out = (float*)d_out;
    (void)in_sizes; (void)n_in; (void)out_size; (void)ws_size;

    const int Bn=4, S=2048, D=512, QKD=256, HID=1536;
    const int M = Bn * S; // 8192
    const long MD = (long)M * D;

    char* p = (char*)d_ws;
    auto alloc = [&](size_t bytes)->void*{ void* r = p; p += (bytes + 255) & ~(size_t)255; return r; };
    u16*  xbf  = (u16*) alloc((size_t)M*D*2);      // reused as nrm_bf after gemm1
    u16*  Wmbf = (u16*) alloc((size_t)D*D*2);
    u8*   Wh8  = (u8*)  alloc((size_t)HID*D);      // v-half fp8
    u16*  Whgb = (u16*) alloc((size_t)HID*D*2);    // gate-half bf16
    u16*  Wqbf = (u16*) alloc((size_t)QKD*D*2);
    u16*  Wobf = (u16*) alloc((size_t)D*HID*2);
    u16*  WbT  = (u16*) alloc((size_t)QKD*QKD*2);
    float* ybuf= (float*)alloc((size_t)MD*4);      // fp32 y
    u16*  wop  = (u16*) alloc((size_t)MD*2*2);     // 2 bf16 split-K partials (Wo)
    u16*  n8   = (u16*) alloc((size_t)M*D);        // nrm fp8*4
    u16*  Zb   = (u16*) alloc((size_t)M*QKD*2);
    u16*  ZWbb = (u16*) alloc((size_t)M*QKD*2);
    u8*   v8   = (u8*)  alloc((size_t)M*HID);
    u16*  gbf  = (u16*) alloc((size_t)M*HID*2);
    u8*   vT8  = (u8*)  alloc((size_t)M*HID);
    u8*   A8   = (u8*)  alloc((size_t)M*S);
    u16*  Vgbf = (u16*) alloc((size_t)M*HID*2);
    u16*  nrm  = xbf;

    dim3 blk(256);

    // 0. casts (Wh v-half fp8, gate-half bf16) + Wb transpose
    castall_k<<<dim3(7040), blk, 0, stream>>>(x, Wm, Wh, Wq, Wo, Wb,
                                              xbf, Wmbf, Wh8, Whgb, Wqbf, Wobf, WbT);
    // 1. y = x@Wm^T + bm + x   (fused epilogue, fp32)
    mgemm<EPI_BIAS_RES,OT_F32><<<dim3(D/128, M/128, 1), blk, 0, stream>>>(
        xbf, Wmbf, ybuf, D, D, D, D, 0,0,0, bm, x, D, 1.f);
    // 2. nrm = LN(y) -> bf16 + fp8*4
    ln1_k<<<dim3(M), blk, 0, stream>>>(ybuf, g1, b1, nrm, n8);
    // 3a. v = relu(nrm8@Wh8^T * 2^-11 + bh) -> fp8*8, MX K=128
    mgemm8mx<true><<<dim3(HID/128, M/128, 1), blk, 0, stream>>>(
        (const u8*)n8, Wh8, nullptr, D, D, D, 0, 0,0,0,
        nullptr, 0, 0, bh, v8);
    // 3b+4. gate = relu(nrm@Whg^T + bh[1536:]) bf16 ; Z = relu(nrm@Wq^T + bq) bf16
    mgemm_dual<<<dim3(14, M/128), blk, 0, stream>>>(
        nrm, Whgb, Wqbf, bh + HID, bq, gbf, Zb);
    // 5. ZWb = Z @ Wb -> bf16
    mgemm<EPI_NONE,OT_BF16><<<dim3(QKD/128, M/128, 1), blk, 0, stream>>>(
        Zb, WbT, ZWbb, QKD, QKD, QKD, QKD, 0,0,0, nullptr, nullptr, 0, 1.f);
    // 6a. A = relu(ZWb_b @ Z_b^T / S)^2 * 2^12 -> fp8, batched over z
    mgemm<EPI_RELUSQ,OT_FP8><<<dim3(S/128, S/128, Bn), blk, 0, stream>>>(
        ZWbb, Zb, A8, QKD, QKD, QKD, S,
        (long)S*QKD, (long)S*QKD, (long)S*S,
        nullptr, nullptr, 0, 1.f/(float)S);
    // 6b. vT = transpose(v) per batch (fp8)
    tr8_k<<<dim3(HID/64, S/64, Bn), blk, 0, stream>>>(v8, vT8, S, HID);
    // 6c. Vg = (A @ v) * 2^-15 * gate -> bf16, MX-fp8 K=128
    mgemm8mx<false><<<dim3(HID/128, S/128, Bn), blk, 0, stream>>>(
        A8, vT8, Vgbf, S, S, S, HID,
        (long)S*S, (long)HID*S, (long)S*HID,
        gbf, HID, (long)S*HID, nullptr, nullptr);
    // 7. t partials = Vg@Wo^T  (split-K z=2, bf16 partials; bias in LN2)
    mgemm<EPI_NONE,OT_BF16><<<dim3(D/128, M/128, 2), blk, 0, stream>>>(
        Vgbf, Wobf, wop, HID/2, HID, HID, D, 768, 768, MD,
        nullptr, nullptr, 0, 1.f);
    // 8. out = LN(p0+p1 + bo) + x
    ln2_k<<<dim3(M), blk, 0, stream>>>(wop, MD, bo, g2, b2, x, out);
}